// Round 1
// baseline (888.631 us; speedup 1.0000x reference)
//
#include <hip/hip_runtime.h>
#include <hip/hip_bf16.h>

typedef short bf16x8 __attribute__((ext_vector_type(8)));
typedef float f32x4 __attribute__((ext_vector_type(4)));

constexpr int NN = 100000;           // nodes
constexpr int NE = 1600000;          // edges
constexpr int HH = 128;              // hidden
constexpr int NR = 8;                // relations
constexpr int NK = NR * NN;          // 800000 (rel,dst) segment keys
constexpr int SCAN_BLOCKS = (NK + 1023) / 1024;   // 782

__device__ __forceinline__ unsigned short f2bf(float f) {
    unsigned b = __float_as_uint(f);
    b += 0x7fffu + ((b >> 16) & 1u);       // round-to-nearest-even
    return (unsigned short)(b >> 16);
}

// ---- W convert + transpose: Wt[L][s][f][d] (bf16) from fp32 W[d][f] ----
// s=0 -> W_root, s=1..8 -> W_rel[s-1]
__global__ void convertW(const float* __restrict__ Wr0, const float* __restrict__ Wq0,
                         const float* __restrict__ Wr1, const float* __restrict__ Wq1,
                         unsigned short* __restrict__ Wt) {
    int o = blockIdx.x * blockDim.x + threadIdx.x;
    if (o >= 2 * 9 * 128 * 128) return;
    int L = o / 147456;
    int rem = o - L * 147456;
    int s = rem >> 14;
    int p = rem & 16383;
    int f = p >> 7;
    int d = p & 127;
    const float* Wq = L ? Wq1 : Wq0;
    const float* Wr = L ? Wr1 : Wr0;
    float v = (s == 0) ? Wq[d * 128 + f] : Wr[((s - 1) * 128 + d) * 128 + f];
    Wt[o] = f2bf(v);
}

// ---- x -> bf16 (with node_idx gather; identity here but cheap) ----
__global__ void convertX(const int* __restrict__ node_idx, const float* __restrict__ emb,
                         unsigned short* __restrict__ xb) {
    int i = blockIdx.x * blockDim.x + threadIdx.x;   // over NN*64 float2s
    if (i >= NN * 64) return;
    int n = i >> 6, dp = i & 63;
    int row = node_idx[n];
    float2 v = *((const float2*)(emb + (size_t)row * HH) + dp);
    unsigned out = (unsigned)f2bf(v.x) | ((unsigned)f2bf(v.y) << 16);
    *((unsigned*)xb + (size_t)n * 64 + dp) = out;
}

// ---- degree count per (rel,dst) key ----
__global__ void countDeg(const int* __restrict__ edst, const int* __restrict__ etype,
                         unsigned* __restrict__ counts) {
    int e = blockIdx.x * blockDim.x + threadIdx.x;
    if (e >= NE) return;
    int key = etype[e] * NN + edst[e];
    atomicAdd(&counts[key], 1u);
}

// ---- 2-level exclusive scan of counts[NK] -> starts ----
__global__ void scan1(const unsigned* __restrict__ counts, unsigned* __restrict__ starts,
                      unsigned* __restrict__ bsums) {
    __shared__ unsigned sh[256];
    int tid = threadIdx.x;
    int base = blockIdx.x * 1024 + tid * 4;
    unsigned c[4], tsum = 0;
#pragma unroll
    for (int j = 0; j < 4; ++j) {
        c[j] = (base + j < NK) ? counts[base + j] : 0u;
        tsum += c[j];
    }
    sh[tid] = tsum;
    __syncthreads();
    for (int ofs = 1; ofs < 256; ofs <<= 1) {
        unsigned v = (tid >= ofs) ? sh[tid - ofs] : 0u;
        __syncthreads();
        sh[tid] += v;
        __syncthreads();
    }
    unsigned run = sh[tid] - tsum;   // exclusive for this thread
#pragma unroll
    for (int j = 0; j < 4; ++j) {
        if (base + j < NK) starts[base + j] = run;
        run += c[j];
    }
    if (tid == 255) bsums[blockIdx.x] = sh[255];
}

__global__ void scan2(unsigned* __restrict__ bsums, int nb) {
    __shared__ unsigned sh[1024];
    int tid = threadIdx.x;
    unsigned v = (tid < nb) ? bsums[tid] : 0u;
    sh[tid] = v;
    __syncthreads();
    for (int ofs = 1; ofs < 1024; ofs <<= 1) {
        unsigned t = (tid >= ofs) ? sh[tid - ofs] : 0u;
        __syncthreads();
        sh[tid] += t;
        __syncthreads();
    }
    if (tid < nb) bsums[tid] = sh[tid] - v;   // exclusive
}

__global__ void scan3(unsigned* __restrict__ starts, unsigned* __restrict__ cursor,
                      const unsigned* __restrict__ bsums) {
    int i = blockIdx.x * blockDim.x + threadIdx.x;
    if (i >= NK) return;
    unsigned v = starts[i] + bsums[i >> 10];
    starts[i] = v;
    cursor[i] = v;
    if (i == 0) starts[NK] = NE;
}

// ---- counting-sort scatter: srcS holds src node per edge, grouped by key ----
__global__ void scatterEdges(const int* __restrict__ esrc, const int* __restrict__ edst,
                             const int* __restrict__ etype, unsigned* __restrict__ cursor,
                             unsigned* __restrict__ srcS) {
    int e = blockIdx.x * blockDim.x + threadIdx.x;
    if (e >= NE) return;
    int key = etype[e] * NN + edst[e];
    unsigned pos = atomicAdd(&cursor[key], 1u);
    srcS[pos] = (unsigned)esrc[e];
}

// ---- per-(rel,dst) mean of bf16 rows: one wave per key ----
__global__ __launch_bounds__(256) void gatherMean(const unsigned* __restrict__ starts,
                                                  const unsigned* __restrict__ srcS,
                                                  const unsigned short* __restrict__ xb,
                                                  unsigned short* __restrict__ h) {
    int key = blockIdx.x * 4 + (threadIdx.x >> 6);
    int lane = threadIdx.x & 63;
    unsigned s0 = starts[key], s1 = starts[key + 1];
    float a0 = 0.f, a1 = 0.f;
    for (unsigned i = s0; i < s1; ++i) {
        unsigned sn = srcS[i];
        unsigned v = *((const unsigned*)xb + (size_t)sn * 64 + lane);
        a0 += __uint_as_float(v << 16);
        a1 += __uint_as_float(v & 0xffff0000u);
    }
    unsigned cnt = s1 - s0;
    if (cnt > 1) {
        float sc = 1.f / (float)cnt;
        a0 *= sc;
        a1 *= sc;
    }
    unsigned out = (unsigned)f2bf(a0) | ((unsigned)f2bf(a1) << 16);
    *((unsigned*)h + (size_t)key * 64 + lane) = out;
}

// ---- fused layer GEMM: out[M,128] = relu([x|h0..h7] @ Wt^T + b) ----
// Tile: 64 nodes x 128 feats per block; 4 waves as 2x2; 16x16x32 bf16 MFMA.
// NOTE: x and outB may alias (layer 0 writes its own rows only) -> no restrict.
__global__ __launch_bounds__(256) void rgcnGemm(const unsigned short* x,
                                                const unsigned short* __restrict__ h,
                                                const unsigned short* __restrict__ Wt,
                                                const float* __restrict__ bias,
                                                float* outF, unsigned short* outB) {
    constexpr int LDA = 136;   // +8 bf16 pad: 272 B row stride, 16B-aligned, ≤2-way banks
    __shared__ __align__(16) unsigned short A_lds[64 * LDA];
    __shared__ __align__(16) unsigned short B_lds[128 * LDA];

    int tid = threadIdx.x;
    int wid = tid >> 6, lane = tid & 63;
    int quad = lane >> 4, l16 = lane & 15;
    int wr = wid >> 1, wc = wid & 1;
    int m0 = blockIdx.x * 64;
    int chunk = tid & 15, rip = tid >> 4;

    f32x4 acc[2][4];
#pragma unroll
    for (int st = 0; st < 2; ++st)
#pragma unroll
        for (int nt = 0; nt < 4; ++nt) acc[st][nt] = (f32x4){0.f, 0.f, 0.f, 0.f};

    for (int s = 0; s < 9; ++s) {
        __syncthreads();
        const unsigned short* Abase = (s == 0) ? x : (h + (size_t)(s - 1) * NN * HH);
#pragma unroll
        for (int p = 0; p < 4; ++p) {
            int r = p * 16 + rip;
            int node = m0 + r;
            node = node < NN ? node : NN - 1;
            uint4 v = *((const uint4*)(Abase + (size_t)node * HH) + chunk);
            *(uint4*)(&A_lds[r * LDA + chunk * 8]) = v;
        }
        const unsigned short* Bbase = Wt + s * 16384;
#pragma unroll
        for (int p = 0; p < 8; ++p) {
            int r = p * 16 + rip;
            uint4 v = *((const uint4*)(Bbase + r * 128) + chunk);
            *(uint4*)(&B_lds[r * LDA + chunk * 8]) = v;
        }
        __syncthreads();
#pragma unroll
        for (int kt = 0; kt < 4; ++kt) {
            int ko = kt * 32 + quad * 8;
            bf16x8 a[2], b[4];
            a[0] = *(const bf16x8*)(&A_lds[(wr * 32 + l16) * LDA + ko]);
            a[1] = *(const bf16x8*)(&A_lds[(wr * 32 + 16 + l16) * LDA + ko]);
#pragma unroll
            for (int nt = 0; nt < 4; ++nt)
                b[nt] = *(const bf16x8*)(&B_lds[(wc * 64 + nt * 16 + l16) * LDA + ko]);
#pragma unroll
            for (int st = 0; st < 2; ++st)
#pragma unroll
                for (int nt = 0; nt < 4; ++nt)
                    acc[st][nt] = __builtin_amdgcn_mfma_f32_16x16x32_bf16(
                        a[st], b[nt], acc[st][nt], 0, 0, 0);
        }
    }
    // epilogue: C/D layout col=lane&15, row=quad*4+reg
#pragma unroll
    for (int st = 0; st < 2; ++st) {
        int rowbase = m0 + wr * 32 + st * 16 + quad * 4;
#pragma unroll
        for (int nt = 0; nt < 4; ++nt) {
            int n = wc * 64 + nt * 16 + l16;
            float bv = bias[n];
#pragma unroll
            for (int rg = 0; rg < 4; ++rg) {
                int node = rowbase + rg;
                if (node < NN) {
                    float v = acc[st][nt][rg] + bv;
                    v = v > 0.f ? v : 0.f;
                    if (outF) outF[(size_t)node * HH + n] = v;
                    else outB[(size_t)node * HH + n] = f2bf(v);
                }
            }
        }
    }
}

extern "C" void kernel_launch(void* const* d_in, const int* in_sizes, int n_in,
                              void* d_out, int out_size, void* d_ws, size_t ws_size,
                              hipStream_t stream) {
    const int* node_idx = (const int*)d_in[0];
    const int* eidx     = (const int*)d_in[1];
    const int* etype    = (const int*)d_in[2];
    const float* emb    = (const float*)d_in[3];
    const float* Wr0    = (const float*)d_in[4];
    const float* Wq0    = (const float*)d_in[5];
    const float* b0     = (const float*)d_in[6];
    const float* Wr1    = (const float*)d_in[7];
    const float* Wq1    = (const float*)d_in[8];
    const float* b1     = (const float*)d_in[9];
    const int* esrc = eidx;
    const int* edst = eidx + NE;

    char* ws = (char*)d_ws;
    size_t off = 0;
    auto alloc = [&](size_t bytes) -> void* {
        void* p = ws + off;
        off = (off + bytes + 255) & ~(size_t)255;
        return p;
    };
    unsigned* counts       = (unsigned*)alloc((size_t)NK * 4);
    unsigned* starts       = (unsigned*)alloc((size_t)(NK + 1) * 4);
    unsigned* cursor       = (unsigned*)alloc((size_t)NK * 4);
    unsigned* bsums        = (unsigned*)alloc(1024 * 4);
    unsigned* srcS         = (unsigned*)alloc((size_t)NE * 4);
    unsigned short* xb     = (unsigned short*)alloc((size_t)NN * HH * 2);
    unsigned short* h      = (unsigned short*)alloc((size_t)NK * HH * 2);
    unsigned short* Wt     = (unsigned short*)alloc((size_t)2 * 9 * 16384 * 2);
    (void)ws_size; (void)n_in; (void)in_sizes; (void)out_size;

    hipMemsetAsync(counts, 0, (size_t)NK * 4, stream);
    convertW<<<(2 * 9 * 16384 + 255) / 256, 256, 0, stream>>>(Wr0, Wq0, Wr1, Wq1, Wt);
    convertX<<<(NN * 64 + 255) / 256, 256, 0, stream>>>(node_idx, emb, xb);
    countDeg<<<(NE + 255) / 256, 256, 0, stream>>>(edst, etype, counts);
    scan1<<<SCAN_BLOCKS, 256, 0, stream>>>(counts, starts, bsums);
    scan2<<<1, 1024, 0, stream>>>(bsums, SCAN_BLOCKS);
    scan3<<<(NK + 255) / 256, 256, 0, stream>>>(starts, cursor, bsums);
    scatterEdges<<<(NE + 255) / 256, 256, 0, stream>>>(esrc, edst, etype, cursor, srcS);

    // layer 0: gather on x, GEMM -> relu -> bf16, written back into xb (own rows only)
    gatherMean<<<NK / 4, 256, 0, stream>>>(starts, srcS, xb, h);
    rgcnGemm<<<(NN + 63) / 64, 256, 0, stream>>>(xb, h, Wt, b0, nullptr, xb);

    // layer 1: gather on relu(out0), GEMM -> relu -> fp32 d_out
    gatherMean<<<NK / 4, 256, 0, stream>>>(starts, srcS, xb, h);
    rgcnGemm<<<(NN + 63) / 64, 256, 0, stream>>>(xb, h, Wt + 147456, b1, (float*)d_out, nullptr);
}